// Round 1
// 433.994 us; speedup vs baseline: 1.0212x; 1.0212x over previous
//
#include <hip/hip_runtime.h>

#define K_DIM 4096
#define N_DIM 8192   // rows of x
#define M_DIM 4096   // rows of weight

typedef int v4i __attribute__((ext_vector_type(4)));

// ---------------- fused amax over x and w ----------------
// blocks [0,2048) reduce x -> scal[0]; blocks [2048,3072) reduce w -> scal[1]
__global__ void amax2_kernel(const float4* __restrict__ x,
                             const float4* __restrict__ w,
                             unsigned* __restrict__ scal) {
  const int XB = 2048, WB = 1024;
  const float4* p;
  int n4, b, nb;
  unsigned* out;
  if (blockIdx.x < XB) {
    p = x; n4 = N_DIM * K_DIM / 4; out = scal + 0; b = blockIdx.x; nb = XB;
  } else {
    p = w; n4 = M_DIM * K_DIM / 4; out = scal + 1; b = blockIdx.x - XB; nb = WB;
  }
  int tid = b * blockDim.x + threadIdx.x;
  int stride = nb * blockDim.x;
  float m = 0.f;
  for (int i = tid; i < n4; i += stride) {
    float4 v = p[i];
    m = fmaxf(m, fmaxf(fmaxf(fabsf(v.x), fabsf(v.y)),
                       fmaxf(fabsf(v.z), fabsf(v.w))));
  }
#pragma unroll
  for (int off = 32; off > 0; off >>= 1)
    m = fmaxf(m, __shfl_down(m, off));
  __shared__ float sm[4];
  int lane = threadIdx.x & 63, wv = threadIdx.x >> 6;
  if (lane == 0) sm[wv] = m;
  __syncthreads();
  if (threadIdx.x == 0) {
    m = fmaxf(fmaxf(sm[0], sm[1]), fmaxf(sm[2], sm[3]));
    atomicMax(out, __float_as_uint(m));  // values >= 0: uint order == float order
  }
}

// ---------------- fused quantize fp32 -> int8, coalesced 4 elems/iter ------
__device__ __forceinline__ unsigned pack4(float4 v, float s) {
  int q0 = (int)fminf(fmaxf(rintf(v.x * s), -127.f), 127.f);
  int q1 = (int)fminf(fmaxf(rintf(v.y * s), -127.f), 127.f);
  int q2 = (int)fminf(fmaxf(rintf(v.z * s), -127.f), 127.f);
  int q3 = (int)fminf(fmaxf(rintf(v.w * s), -127.f), 127.f);
  return (unsigned)(q0 & 255) | ((unsigned)(q1 & 255) << 8) |
         ((unsigned)(q2 & 255) << 16) | ((unsigned)(q3 & 255) << 24);
}

__global__ void quant2_kernel(const float4* __restrict__ x,
                              const float4* __restrict__ w,
                              unsigned* __restrict__ qx, unsigned* __restrict__ qw,
                              const unsigned* __restrict__ scal) {
  const int XB = 2048, WB = 1024;
  const float4* in;
  unsigned* out;
  int n4, b, nb;
  float amax;
  if (blockIdx.x < XB) {
    in = x; out = qx; n4 = N_DIM * K_DIM / 4; b = blockIdx.x; nb = XB;
    amax = __uint_as_float(scal[0]);
  } else {
    in = w; out = qw; n4 = M_DIM * K_DIM / 4; b = blockIdx.x - XB; nb = WB;
    amax = __uint_as_float(scal[1]);
  }
  float s = 127.0f / amax;
  int tid = b * blockDim.x + threadIdx.x;
  int stride = nb * blockDim.x;
  // 16B load / 4B store per lane per iter: fully coalesced per instruction
  for (int i = tid; i < n4; i += stride) out[i] = pack4(in[i], s);
}

// ---------------- int8 GEMM: out = qx (N,K) * qw^T (K,M), dequant + bias ----
__device__ __forceinline__ void gld_lds16(const void* g, void* l) {
  __builtin_amdgcn_global_load_lds(
      (const __attribute__((address_space(1))) void*)g,
      (__attribute__((address_space(3))) void*)l, 16, 0, 0);
}

// 256x256 tile, BK=128 bytes, 8 waves (2M x 4N), double-buffered 128 KiB LDS.
// XOR-swizzled LDS (chunk c of a row holds global chunk c^(row&7)), staged via
// pre-swizzled global source + linear global_load_lds dest (both-sides rule).
// Counted vmcnt(8): the 8 global_load_lds for tile t+1 stay in flight across
// the barriers while tile t computes (T3/T4); s_setprio around MFMA (T5).
__global__ __launch_bounds__(512, 2) void gemm_i8(
    const signed char* __restrict__ A,   // qx  [N_DIM][K_DIM]
    const signed char* __restrict__ B,   // qw  [M_DIM][K_DIM]
    const float* __restrict__ bias,      // [M_DIM]
    float* __restrict__ out,             // [N_DIM][M_DIM]
    const unsigned* __restrict__ scal)   // [0]=amax_x bits [1]=amax_w bits
{
  __shared__ signed char lds[2][2][256 * 128];  // [buf][A/B][rows*K-bytes] = 128 KiB

  const int tid = threadIdx.x;
  const int lane = tid & 63;
  const int w = tid >> 6;      // wave 0..7
  const int wm = w >> 2;       // 0..1  (row half of 256)
  const int wn = w & 3;        // 0..3  (col quarter of 256)
  const long r0 = (long)blockIdx.x * 256;
  const long c0 = (long)blockIdx.y * 256;

  // staging: per pass p (0..3): row = p*64 + (tid>>3), LDS chunk = tid&7,
  // which must hold global chunk (tid&7) ^ (row&7); row&7 == (tid>>3)&7.
  const int srow = tid >> 3;                       // 0..63
  const int gcol = ((tid & 7) ^ (srow & 7)) * 16;  // swizzled source column
  const signed char* ga = A + (r0 + srow) * K_DIM + gcol;
  const signed char* gb = B + (c0 + srow) * K_DIM + gcol;
  const int ldst = tid * 16;  // == (tid>>3)*128 + (tid&7)*16 : linear dest

  v4i acc[8][4];
#pragma unroll
  for (int i = 0; i < 8; ++i)
#pragma unroll
    for (int j = 0; j < 4; ++j) acc[i][j] = (v4i){0, 0, 0, 0};

  const int fr = lane & 15;   // fragment row (m or n)
  const int fq = lane >> 4;   // k-quad
  const int sa = fr & 7;      // swizzle key for fragment reads

  auto STAGE = [&](int t, int buf) {
    const long ko = (long)t * 128;
    signed char* la = &lds[buf][0][0];
    signed char* lb = &lds[buf][1][0];
#pragma unroll
    for (int p = 0; p < 4; ++p)
      gld_lds16(ga + (long)p * 64 * K_DIM + ko, la + p * 8192 + ldst);
#pragma unroll
    for (int p = 0; p < 4; ++p)
      gld_lds16(gb + (long)p * 64 * K_DIM + ko, lb + p * 8192 + ldst);
  };

  auto COMPUTE = [&](int buf) {
    const signed char* la = &lds[buf][0][0];
    const signed char* lb = &lds[buf][1][0];
#pragma unroll
    for (int ks = 0; ks < 2; ++ks) {
      const int co = ((ks * 4 + fq) ^ sa) * 16;
      v4i bv[4];
#pragma unroll
      for (int nf = 0; nf < 4; ++nf)
        bv[nf] = *(const v4i*)(lb + (wn * 64 + nf * 16 + fr) * 128 + co);
#pragma unroll
      for (int mh = 0; mh < 2; ++mh) {
        v4i av[4];
#pragma unroll
        for (int mi = 0; mi < 4; ++mi)
          av[mi] =
              *(const v4i*)(la + (wm * 128 + mh * 64 + mi * 16 + fr) * 128 + co);
        __builtin_amdgcn_s_setprio(1);
#pragma unroll
        for (int mi = 0; mi < 4; ++mi)
#pragma unroll
          for (int nf = 0; nf < 4; ++nf)
            acc[mh * 4 + mi][nf] = __builtin_amdgcn_mfma_i32_16x16x64_i8(
                av[mi], bv[nf], acc[mh * 4 + mi][nf], 0, 0, 0);
        __builtin_amdgcn_s_setprio(0);
      }
    }
  };

  const int NT = K_DIM / 128;  // 32 K-tiles
  STAGE(0, 0);
  STAGE(1, 1);
  for (int t = 0; t < NT - 1; ++t) {
    // tile t's 8 loads are the oldest; leave tile t+1's 8 in flight
    asm volatile("s_waitcnt vmcnt(8)" ::: "memory");
    __builtin_amdgcn_s_barrier();
    COMPUTE(t & 1);
    __builtin_amdgcn_s_barrier();  // all waves done reading buf before overwrite
    if (t + 2 < NT) STAGE(t + 2, t & 1);
  }
  asm volatile("s_waitcnt vmcnt(0)" ::: "memory");
  __builtin_amdgcn_s_barrier();
  COMPUTE((NT - 1) & 1);

  const float dq =
      (__uint_as_float(scal[0]) * __uint_as_float(scal[1])) / 16129.0f;
  float bs[4];
#pragma unroll
  for (int nf = 0; nf < 4; ++nf) bs[nf] = bias[c0 + wn * 64 + nf * 16 + fr];

#pragma unroll
  for (int mf = 0; mf < 8; ++mf) {
    const long rbase = r0 + wm * 128 + mf * 16 + fq * 4;  // C/D row=(lane>>4)*4+reg
#pragma unroll
    for (int nf = 0; nf < 4; ++nf) {
      const long c = c0 + wn * 64 + nf * 16 + fr;         // C/D col=lane&15
#pragma unroll
      for (int t = 0; t < 4; ++t) {
        out[(rbase + t) * (long)M_DIM + c] = (float)acc[mf][nf][t] * dq + bs[nf];
      }
    }
  }
}

extern "C" void kernel_launch(void* const* d_in, const int* in_sizes, int n_in,
                              void* d_out, int out_size, void* d_ws, size_t ws_size,
                              hipStream_t stream) {
  const float* x = (const float*)d_in[0];      // [8192,4096]
  const float* wt = (const float*)d_in[1];     // [4096,4096]
  const float* bias = (const float*)d_in[2];   // [4096]
  float* out = (float*)d_out;

  unsigned* scal = (unsigned*)d_ws;                       // 2 scalars
  signed char* qx = (signed char*)d_ws + 256;             // 32 MiB
  signed char* qw = qx + (long)N_DIM * K_DIM;             // 16 MiB

  hipMemsetAsync(d_ws, 0, 16, stream);  // zero amax slots (ws poisoned 0xAA)

  amax2_kernel<<<3072, 256, 0, stream>>>((const float4*)x, (const float4*)wt,
                                         scal);
  quant2_kernel<<<3072, 256, 0, stream>>>((const float4*)x, (const float4*)wt,
                                          (unsigned*)qx, (unsigned*)qw, scal);

  dim3 grid(N_DIM / 256, M_DIM / 256);  // 32 x 16
  gemm_i8<<<grid, 512, 0, stream>>>(qx, qw, bias, out, scal);
}